// Round 1
// baseline (488.295 us; speedup 1.0000x reference)
//
#include <hip/hip_runtime.h>
#include <math.h>

#define SCALE_ 0.08838834764831845f   // 1/sqrt(128)
#define MINV_  (-3.4028234663852886e38f)

typedef __bf16 bf16;
typedef bf16  bf16x4 __attribute__((ext_vector_type(4)));
typedef bf16  bf16x8 __attribute__((ext_vector_type(8)));
typedef float f32x4  __attribute__((ext_vector_type(4)));
typedef float float4v __attribute__((ext_vector_type(4)));

#define LD8(p) (*(const bf16x8*)(p))

__device__ __forceinline__ f32x4 mfma16(bf16x8 a, bf16x8 b, f32x4 c) {
    return __builtin_amdgcn_mfma_f32_16x16x32_bf16(a, b, c, 0, 0, 0);
}

// ---------------- prep kernels ----------------

__global__ __launch_bounds__(256) void cast_hidden_kernel(const float* __restrict__ X, bf16* __restrict__ Y)
{
    int i = (blockIdx.x * 256 + threadIdx.x) * 4;
    float4v v = *(const float4v*)(X + i);
    bf16x4 o; o.x = (bf16)v.x; o.y = (bf16)v.y; o.z = (bf16)v.z; o.w = (bf16)v.w;
    *(bf16x4*)(Y + i) = o;
}

// BT[n][k] = W[k][src(n)]; qmap: src = (n>>7)*384 + (n&127) (q columns of Wqkv), else src=n (Wo)
__global__ __launch_bounds__(256) void transpose_cast_kernel(const float* __restrict__ W, bf16* __restrict__ BT,
                                                             int srcStride, int qmap)
{
    __shared__ float tile[32][33];
    int k0 = blockIdx.x * 32, n0 = blockIdx.y * 32;
    int c = threadIdx.x & 31, r = threadIdx.x >> 5;   // r in 0..7
    int n = n0 + c;
    int src = qmap ? ((n >> 7) * 384 + (n & 127)) : n;
    #pragma unroll
    for (int rr = 0; rr < 32; rr += 8)
        tile[r + rr][c] = W[(size_t)(k0 + r + rr) * srcStride + src];
    __syncthreads();
    #pragma unroll
    for (int rr = 0; rr < 32; rr += 8)
        BT[(size_t)(n0 + r + rr) * 2048 + k0 + c] = (bf16)tile[c][r + rr];
}

// rows 2048..2303 of BT1: head-averaged k/v weight columns.
// j in [0,256): src col = h*384 + 128 + j  (j<128 -> k part, j>=128 -> v part since +256 = +128+j)
__global__ __launch_bounds__(256) void bt1_kv_kernel(const float* __restrict__ Wqkv, bf16* __restrict__ BT1)
{
    int k = blockIdx.x * 256 + threadIdx.x;   // 0..2047
    int j = blockIdx.y;                       // 0..255
    float s = 0.f;
    #pragma unroll
    for (int h = 0; h < 16; h++) s += Wqkv[(size_t)k * 6144 + h * 384 + 128 + j];
    BT1[(size_t)(2048 + j) * 2048 + k] = (bf16)(s * 0.0625f);
}

__global__ void bias1_kernel(const float* __restrict__ bqkv, float* __restrict__ bias1)
{
    int c = blockIdx.x * 256 + threadIdx.x;
    if (c >= 2304) return;
    if (c < 2048) bias1[c] = bqkv[(c >> 7) * 384 + (c & 127)];
    else {
        int j = c - 2048; float s = 0.f;
        for (int h = 0; h < 16; h++) s += bqkv[h * 384 + 128 + j];
        bias1[c] = s * 0.0625f;
    }
}

// ---------------- GEMM: C[m][n] = A[m][:] . BT[n][:] + bias[n] ----------------
// 128x128 block tile, BK=32, 4 waves (2x2), 4x4 16x16 tiles per wave.
template<int OUT_BF16>
__global__ __launch_bounds__(256) void gemm_kernel(const bf16* __restrict__ A, const bf16* __restrict__ BT,
                                                   const float* __restrict__ bias, void* __restrict__ Cout,
                                                   int M, int N, int K)
{
    __shared__ bf16 As[128 * 32];
    __shared__ bf16 Bs[128 * 32];
    const int tid  = threadIdx.x;
    const int wv   = tid >> 6, lane = tid & 63, quad = lane >> 4, l16 = lane & 15;
    const int wrow = wv >> 1, wcol = wv & 1;
    const int m0 = blockIdx.y * 128, n0 = blockIdx.x * 128;

    const int srow = tid >> 1, scol = (tid & 1) * 16;
    const bf16* Ag = A  + (size_t)(m0 + srow) * K + scol;
    const bf16* Bg = BT + (size_t)(n0 + srow) * K + scol;

    f32x4 acc[4][4];
    #pragma unroll
    for (int i = 0; i < 4; i++)
        #pragma unroll
        for (int j = 0; j < 4; j++) acc[i][j] = (f32x4){0.f, 0.f, 0.f, 0.f};

    for (int kk = 0; kk < K; kk += 32) {
        bf16x8 av0 = LD8(Ag + kk);
        bf16x8 av1 = LD8(Ag + kk + 8);
        bf16x8 bv0 = LD8(Bg + kk);
        bf16x8 bv1 = LD8(Bg + kk + 8);
        *(bf16x8*)&As[srow * 32 + scol]     = av0;
        *(bf16x8*)&As[srow * 32 + scol + 8] = av1;
        *(bf16x8*)&Bs[srow * 32 + scol]     = bv0;
        *(bf16x8*)&Bs[srow * 32 + scol + 8] = bv1;
        __syncthreads();
        bf16x8 af[4], bfr[4];
        #pragma unroll
        for (int i = 0; i < 4; i++) af[i]  = LD8(&As[(wrow * 64 + i * 16 + l16) * 32 + quad * 8]);
        #pragma unroll
        for (int j = 0; j < 4; j++) bfr[j] = LD8(&Bs[(wcol * 64 + j * 16 + l16) * 32 + quad * 8]);
        #pragma unroll
        for (int i = 0; i < 4; i++)
            #pragma unroll
            for (int j = 0; j < 4; j++)
                acc[i][j] = mfma16(af[i], bfr[j], acc[i][j]);
        __syncthreads();
    }

    #pragma unroll
    for (int i = 0; i < 4; i++) {
        #pragma unroll
        for (int j = 0; j < 4; j++) {
            int n = n0 + wcol * 64 + j * 16 + l16;
            float bn = bias[n];
            #pragma unroll
            for (int r = 0; r < 4; r++) {
                int m = m0 + wrow * 64 + i * 16 + quad * 4 + r;
                float v = acc[i][j][r] + bn;
                if (OUT_BF16) ((bf16*)Cout)[(size_t)m * N + n] = (bf16)v;
                else          ((float*)Cout)[(size_t)m * N + n] = v;
            }
        }
    }
}

// ---------------- rotary (in-place on C1 bf16): q (16 heads) + k_mean, first 32 dims ----------------
__global__ __launch_bounds__(320) void rotary_kernel(bf16* __restrict__ C1)
{
    int row = blockIdx.x;          // b*2048 + s
    int s = row & 2047;
    int t = threadIdx.x;
    if (t >= 272) return;          // 17 groups (16 q heads + k_mean) x 16 dim-pairs
    int g = t >> 4, dd = t & 15;
    bf16* ptr = C1 + (size_t)row * 2304 + (g < 16 ? g * 128 : 2048);
    float x0 = (float)ptr[dd], x1 = (float)ptr[dd + 16];
    const float L = 0.575646273248511f;  // ln(10000)/16
    float inv = expf(-L * (float)dd);
    float ang = (float)s * inv;
    float c = cosf(ang), si = sinf(ang);
    ptr[dd]      = (bf16)(x0 * c - x1 * si);
    ptr[dd + 16] = (bf16)(x1 * c + x0 * si);
}

// ---------------- vmT[b][d][s] = v_mean, transposed; vgT[b][d][g] = gathered global v ----------------
__global__ __launch_bounds__(256) void build_vmT_kernel(const bf16* __restrict__ C1, bf16* __restrict__ vmT)
{
    __shared__ float tile[32][33];
    int b = blockIdx.z;
    int s0 = blockIdx.x * 32, d0 = blockIdx.y * 32;
    int c = threadIdx.x & 31, r = threadIdx.x >> 5;
    #pragma unroll
    for (int rr = 0; rr < 32; rr += 8)
        tile[r + rr][c] = (float)C1[(size_t)(b * 2048 + s0 + r + rr) * 2304 + 2176 + d0 + c];
    __syncthreads();
    #pragma unroll
    for (int rr = 0; rr < 32; rr += 8)
        vmT[(size_t)(b * 128 + d0 + r + rr) * 2048 + s0 + c] = (bf16)tile[c][r + rr];
}

__global__ void build_vgT_kernel(const bf16* __restrict__ C1, const int* __restrict__ gidx, bf16* __restrict__ vgT)
{
    int b = blockIdx.x;
    for (int i = threadIdx.x; i < 128 * 64; i += 256) {
        int d = i >> 6, g = i & 63;
        int pos = gidx[b * 64 + g];
        vgT[(size_t)(b * 128 + d) * 64 + g] = C1[(size_t)(b * 2048 + pos) * 2304 + 2176 + d];
    }
}

// ---------------- attention, first WIN=256 queries (causal), block per (qtile16, h, b) ----------------
__global__ __launch_bounds__(256) void attn0_kernel(const bf16* __restrict__ C1, const bf16* __restrict__ vmT,
                                                    const float* __restrict__ mask, bf16* __restrict__ attn)
{
    int qt = blockIdx.x, h = blockIdx.y, b = blockIdx.z;
    int tid = threadIdx.x, wv = tid >> 6, lane = tid & 63, quad = lane >> 4, l16 = lane & 15;
    int q0 = qt * 16;

    __shared__ float s_s[16][264];
    __shared__ bf16  p_s[16][272];
    __shared__ float inv_l[16];

    // QK^T: M=16 queries, N=256 keys, K=128
    bf16x8 af[4];
    const bf16* qbase = C1 + (size_t)(b * 2048 + q0 + l16) * 2304 + h * 128;
    #pragma unroll
    for (int ks = 0; ks < 4; ks++) af[ks] = LD8(qbase + ks * 32 + quad * 8);

    f32x4 acc[4];
    #pragma unroll
    for (int t = 0; t < 4; t++) acc[t] = (f32x4){0.f, 0.f, 0.f, 0.f};
    #pragma unroll
    for (int t = 0; t < 4; t++) {
        int key = (wv * 4 + t) * 16 + l16;
        const bf16* kb = C1 + (size_t)(b * 2048 + key) * 2304 + 2048;
        #pragma unroll
        for (int ks = 0; ks < 4; ks++)
            acc[t] = mfma16(af[ks], LD8(kb + ks * 32 + quad * 8), acc[t]);
    }
    #pragma unroll
    for (int t = 0; t < 4; t++) {
        int key = (wv * 4 + t) * 16 + l16;
        float mval = mask[b * 2048 + key];
        #pragma unroll
        for (int r = 0; r < 4; r++) {
            int qq = q0 + quad * 4 + r;
            float s = acc[t][r] * SCALE_;
            if (key > qq) s = MINV_;
            s_s[quad * 4 + r][key] = s + mval;
        }
    }
    __syncthreads();

    // softmax: group g = query row, 16 lanes scan 16 cols each
    int g = tid >> 4, lg = tid & 15;
    float vals[16];
    float mx = MINV_;
    #pragma unroll
    for (int i = 0; i < 16; i++) { vals[i] = s_s[g][lg + 16 * i]; mx = fmaxf(mx, vals[i]); }
    #pragma unroll
    for (int m = 1; m < 16; m <<= 1) mx = fmaxf(mx, __shfl_xor(mx, m, 64));
    float l = 0.f;
    #pragma unroll
    for (int i = 0; i < 16; i++) { float e = expf(vals[i] - mx); l += e; p_s[g][lg + 16 * i] = (bf16)e; }
    #pragma unroll
    for (int m = 1; m < 16; m <<= 1) l += __shfl_xor(l, m, 64);
    if (lg == 0) inv_l[g] = 1.0f / l;
    __syncthreads();

    // PV: M=16 queries, N=128 dims (wave -> 32 dims), K=256 keys
    f32x4 o[2];
    o[0] = (f32x4){0.f, 0.f, 0.f, 0.f}; o[1] = (f32x4){0.f, 0.f, 0.f, 0.f};
    #pragma unroll
    for (int ks = 0; ks < 8; ks++) {
        bf16x8 pa = LD8(&p_s[l16][ks * 32 + quad * 8]);
        #pragma unroll
        for (int t = 0; t < 2; t++) {
            int d = wv * 32 + t * 16 + l16;
            bf16x8 vb = LD8(vmT + (size_t)(b * 128 + d) * 2048 + ks * 32 + quad * 8);
            o[t] = mfma16(pa, vb, o[t]);
        }
    }
    #pragma unroll
    for (int t = 0; t < 2; t++) {
        int d = wv * 32 + t * 16 + l16;
        #pragma unroll
        for (int r = 0; r < 4; r++) {
            int qq = q0 + quad * 4 + r;
            attn[(size_t)(b * 2048 + qq) * 2048 + h * 128 + d] = (bf16)(o[t][r] * inv_l[quad * 4 + r]);
        }
    }
}

// ---------------- attention, steps (query p = 256+step): 64 global + 256 window keys, all 16 heads ----------------
__global__ __launch_bounds__(256) void attn_steps_kernel(const bf16* __restrict__ C1, const bf16* __restrict__ vmT,
                                                         const bf16* __restrict__ vgT, const float* __restrict__ mask,
                                                         const int* __restrict__ gidx, bf16* __restrict__ attn)
{
    int step = blockIdx.x, b = blockIdx.y;
    int p = 256 + step;
    int tid = threadIdx.x, wv = tid >> 6, lane = tid & 63, quad = lane >> 4, l16 = lane & 15;

    __shared__ float s_s[16][324];
    __shared__ bf16  p_s[16][328];
    __shared__ int   gixs[64];
    __shared__ float inv_l[16];

    if (tid < 64) gixs[tid] = gidx[b * 64 + tid];
    __syncthreads();

    // QK^T: M=16 heads, N=320 keys (64 glob + 256 win), K=128
    bf16x8 af[4];
    const bf16* qbase = C1 + (size_t)(b * 2048 + p) * 2304 + l16 * 128;
    #pragma unroll
    for (int ks = 0; ks < 4; ks++) af[ks] = LD8(qbase + ks * 32 + quad * 8);

    f32x4 acc[5];
    #pragma unroll
    for (int t = 0; t < 5; t++) acc[t] = (f32x4){0.f, 0.f, 0.f, 0.f};
    #pragma unroll
    for (int t = 0; t < 5; t++) {
        int key = (wv * 5 + t) * 16 + l16;
        int pos = (key < 64) ? gixs[key] : (step + 1 + key - 64);
        const bf16* kb = C1 + (size_t)(b * 2048 + pos) * 2304 + 2048;
        #pragma unroll
        for (int ks = 0; ks < 4; ks++)
            acc[t] = mfma16(af[ks], LD8(kb + ks * 32 + quad * 8), acc[t]);
    }
    #pragma unroll
    for (int t = 0; t < 5; t++) {
        int key = (wv * 5 + t) * 16 + l16;
        bool isglob = (key < 64);
        bool inval = isglob && !(gixs[key] < step);
        float addv = isglob ? 0.f : mask[b * 2048 + step + 1 + key - 64];
        #pragma unroll
        for (int r = 0; r < 4; r++) {
            float s = acc[t][r] * SCALE_;
            s = inval ? MINV_ : (s + addv);
            s_s[quad * 4 + r][key] = s;
        }
    }
    __syncthreads();

    // softmax over 320, group g = head
    int g = tid >> 4, lg = tid & 15;
    float vals[20];
    float mx = MINV_;
    #pragma unroll
    for (int i = 0; i < 20; i++) { vals[i] = s_s[g][lg + 16 * i]; mx = fmaxf(mx, vals[i]); }
    #pragma unroll
    for (int m = 1; m < 16; m <<= 1) mx = fmaxf(mx, __shfl_xor(mx, m, 64));
    float l = 0.f;
    #pragma unroll
    for (int i = 0; i < 20; i++) { float e = expf(vals[i] - mx); l += e; p_s[g][lg + 16 * i] = (bf16)e; }
    #pragma unroll
    for (int m = 1; m < 16; m <<= 1) l += __shfl_xor(l, m, 64);
    if (lg == 0) inv_l[g] = 1.0f / l;
    __syncthreads();

    // PV: M=16 heads, N=128 dims (wave -> 32), K=320 keys
    f32x4 o[2];
    o[0] = (f32x4){0.f, 0.f, 0.f, 0.f}; o[1] = (f32x4){0.f, 0.f, 0.f, 0.f};
    #pragma unroll
    for (int ks = 0; ks < 10; ks++) {
        bf16x8 pa = LD8(&p_s[l16][ks * 32 + quad * 8]);
        #pragma unroll
        for (int t = 0; t < 2; t++) {
            int d = wv * 32 + t * 16 + l16;
            const bf16* vb;
            if (ks < 2) vb = vgT + (size_t)(b * 128 + d) * 64 + ks * 32 + quad * 8;
            else        vb = vmT + (size_t)(b * 128 + d) * 2048 + (step + 1) + (ks - 2) * 32 + quad * 8;
            o[t] = mfma16(pa, LD8(vb), o[t]);
        }
    }
    #pragma unroll
    for (int t = 0; t < 2; t++) {
        int d = wv * 32 + t * 16 + l16;
        #pragma unroll
        for (int r = 0; r < 4; r++) {
            int h = quad * 4 + r;
            attn[(size_t)(b * 2048 + p) * 2048 + h * 128 + d] = (bf16)(o[t][r] * inv_l[h]);
        }
    }
}

// ---------------- launch ----------------
extern "C" void kernel_launch(void* const* d_in, const int* in_sizes, int n_in,
                              void* d_out, int out_size, void* d_ws, size_t ws_size,
                              hipStream_t stream)
{
    const float* hidden = (const float*)d_in[0];
    const float* amask  = (const float*)d_in[1];
    const int*   gidx   = (const int*)d_in[2];
    const float* Wqkv   = (const float*)d_in[3];
    const float* bqkv   = (const float*)d_in[4];
    const float* Wo     = (const float*)d_in[5];
    const float* bo     = (const float*)d_in[6];

    char* ws = (char*)d_ws;
    size_t off = 0;
    auto take = [&](size_t bytes) -> char* {
        char* p = ws + off;
        off = (off + bytes + 255) & ~(size_t)255;
        return p;
    };
    bf16*  A16   = (bf16*)take(4096ull * 2048 * 2);   // hidden, bf16
    bf16*  BT1   = (bf16*)take(2304ull * 2048 * 2);   // [q cols | k-avg | v-avg]^T
    bf16*  BT2   = (bf16*)take(2048ull * 2048 * 2);   // Wo^T
    bf16*  C1    = (bf16*)take(4096ull * 2304 * 2);   // q(2048) | k_mean(128) | v_mean(128)
    bf16*  vmT   = (bf16*)take(2ull * 128 * 2048 * 2);
    bf16*  vgT   = (bf16*)take(2ull * 128 * 64 * 2);
    bf16*  attnb = (bf16*)take(4096ull * 2048 * 2);
    float* bias1 = (float*)take(2304 * 4);

    cast_hidden_kernel<<<8192, 256, 0, stream>>>(hidden, A16);
    transpose_cast_kernel<<<dim3(64, 64), 256, 0, stream>>>(Wqkv, BT1, 6144, 1);
    bt1_kv_kernel<<<dim3(8, 256), 256, 0, stream>>>(Wqkv, BT1);
    bias1_kernel<<<9, 256, 0, stream>>>(bqkv, bias1);
    transpose_cast_kernel<<<dim3(64, 64), 256, 0, stream>>>(Wo, BT2, 2048, 0);

    gemm_kernel<1><<<dim3(18, 32), 256, 0, stream>>>(A16, BT1, bias1, (void*)C1, 4096, 2304, 2048);

    rotary_kernel<<<4096, 320, 0, stream>>>(C1);
    build_vmT_kernel<<<dim3(64, 4, 2), 256, 0, stream>>>(C1, vmT);
    build_vgT_kernel<<<2, 256, 0, stream>>>(C1, gidx, vgT);

    attn0_kernel<<<dim3(16, 16, 2), 256, 0, stream>>>(C1, vmT, amask, attnb);
    attn_steps_kernel<<<dim3(1792, 2), 256, 0, stream>>>(C1, vmT, vgT, amask, gidx, attnb);

    gemm_kernel<0><<<dim3(16, 32), 256, 0, stream>>>(attnb, BT2, bo, d_out, 4096, 2048, 2048);

    (void)in_sizes; (void)n_in; (void)out_size; (void)ws_size;
}